// Round 4
// baseline (223.497 us; speedup 1.0000x reference)
//
#include <hip/hip_runtime.h>
#include <math.h>

typedef __bf16 bf16_t;
typedef bf16_t bf16x8 __attribute__((ext_vector_type(8)));
typedef bf16_t bf16x4 __attribute__((ext_vector_type(4)));
typedef float  f32x4  __attribute__((ext_vector_type(4)));
typedef float  floatv4 __attribute__((ext_vector_type(4)));

#define AS1 __attribute__((address_space(1)))
#define AS3 __attribute__((address_space(3)))

static __device__ __forceinline__ void gld_lds16(const void* g, void* l) {
  __builtin_amdgcn_global_load_lds((const AS1 unsigned int*)g,
                                   (AS3 unsigned int*)l, 16, 0, 0);
}
static __device__ __forceinline__ void block_sync() {
  asm volatile("" ::: "memory");
  __builtin_amdgcn_s_barrier();
  asm volatile("" ::: "memory");
}

// ---------------- cast f32 -> bf16, 4 elems/thread ----------------
__global__ __launch_bounds__(256) void k_cast(const float* __restrict__ in,
                                              bf16_t* __restrict__ out, int n4) {
  int i = blockIdx.x * 256 + threadIdx.x;
  if (i >= n4) return;
  floatv4 v = ((const floatv4*)in)[i];
  bf16x4 o;
  o.x = (bf16_t)v.x; o.y = (bf16_t)v.y; o.z = (bf16_t)v.z; o.w = (bf16_t)v.w;
  ((bf16x4*)out)[i] = o;
}

// ---------------- transpose + cast: in f32 [R][Cc] -> out bf16 [Cc][R] ----------------
__global__ __launch_bounds__(256) void k_transpose_cast(const float* __restrict__ in,
                                                        bf16_t* __restrict__ out,
                                                        int R, int Cc) {
  __shared__ float tile[32][33];
  int c0 = blockIdx.x * 32, r0 = blockIdx.y * 32;
  int tx = threadIdx.x, ty = threadIdx.y;  // 32 x 8
#pragma unroll
  for (int i = 0; i < 32; i += 8)
    tile[ty + i][tx] = in[(size_t)(r0 + ty + i) * Cc + c0 + tx];
  __syncthreads();
#pragma unroll
  for (int i = 0; i < 32; i += 8)
    out[(size_t)(c0 + ty + i) * R + r0 + tx] = (bf16_t)tile[tx][ty + i];
}

// ---------------- GEMM1 v2: fragment-order LDS, 2-phase pipeline, LDS epilogue ----------------
// LDS per buf (16KB): A subtiles 0..7 (16 rows x 32 k each) at byte s*1024 + lane*16,
// B likewise at +8192. Fragment read = base + lane*16 (conflict-free).
__global__ __launch_bounds__(256) void k_gemm_qkv(
    const bf16_t* __restrict__ A, const bf16_t* __restrict__ Bt,
    const float* __restrict__ bias,
    bf16_t* __restrict__ qo, bf16_t* __restrict__ ko, bf16_t* __restrict__ vto) {
  const int K = 1024;
  __shared__ __align__(16) char smem[33792];  // staging 2x16KB; epilogue [128][132] bf16
  const int m0 = blockIdx.x * 128, n0 = blockIdx.y * 128;
  const int t = threadIdx.x, lane = t & 63, w = t >> 6;
  const int wr = w >> 1, wc = w & 1;
  const int ln15 = lane & 15, lhi = lane >> 4;

  f32x4 acc[4][4];
#pragma unroll
  for (int m = 0; m < 4; ++m)
#pragma unroll
    for (int n = 0; n < 4; ++n) acc[m][n] = (f32x4){0.f, 0.f, 0.f, 0.f};

  // staging: thread stages subtiles s = w (p=0) and s = w+4 (p=1) of A and B
  const bf16_t* aSrc = A + (size_t)(m0 + w * 16 + ln15) * K + lhi * 8;
  const bf16_t* bSrc = Bt + (size_t)(n0 + w * 16 + ln15) * K + lhi * 8;
  char* dstA = smem + t * 16;

  auto stageG = [&](int k0, int buf) {
    char* base = dstA + buf * 16384;
    gld_lds16(aSrc + k0, base);
    gld_lds16(aSrc + 64 * K + k0, base + 4096);
    gld_lds16(bSrc + k0, base + 8192);
    gld_lds16(bSrc + 64 * K + k0, base + 12288);
  };

  stageG(0, 0);
  asm volatile("s_waitcnt vmcnt(0)" ::: "memory");
  block_sync();
  int buf = 0;
#pragma unroll 2
  for (int it = 0; it < 32; ++it) {
    if (it + 1 < 32) stageG((it + 1) * 32, buf ^ 1);
    const bf16_t* Asb = (const bf16_t*)(smem + buf * 16384);
    const bf16_t* Bsb = (const bf16_t*)(smem + buf * 16384 + 8192);
    bf16x8 af[4], bfr[4];
#pragma unroll
    for (int m = 0; m < 4; ++m)
      af[m] = *(const bf16x8*)(Asb + (wr * 4 + m) * 512 + lane * 8);
#pragma unroll
    for (int n = 0; n < 4; ++n)
      bfr[n] = *(const bf16x8*)(Bsb + (wc * 4 + n) * 512 + lane * 8);
#pragma unroll
    for (int m = 0; m < 4; ++m)
#pragma unroll
      for (int n = 0; n < 4; ++n)
        acc[m][n] = __builtin_amdgcn_mfma_f32_16x16x32_bf16(af[m], bfr[n], acc[m][n], 0, 0, 0);
    asm volatile("s_waitcnt vmcnt(0)" ::: "memory");
    block_sync();
    buf ^= 1;
  }

  // epilogue: through LDS for coalesced 16B stores
  bf16_t* L = (bf16_t*)smem;  // [128][132]
  const int which = n0 >> 10;  // uniform: 0=q 1=k 2=v
  const float bscale = (which == 0) ? 0.18033688011112042f : 1.0f;  // 0.125*log2(e)
#pragma unroll
  for (int n = 0; n < 4; ++n) {
    const int col = wc * 64 + n * 16 + ln15;
    const float bv = bias[n0 + col];
#pragma unroll
    for (int m = 0; m < 4; ++m)
#pragma unroll
      for (int j = 0; j < 4; ++j) {
        const int row = wr * 64 + m * 16 + lhi * 4 + j;
        const bf16_t ob = (bf16_t)((acc[m][n][j] + bv) * bscale);
        if (which == 2) L[col * 132 + row] = ob;
        else            L[row * 132 + col] = ob;
      }
  }
  block_sync();
  const int bq = m0 >> 11, ttb = m0 & 2047;
  if (which == 2) {
#pragma unroll
    for (int c = 0; c < 8; ++c) {
      const int idx = c * 256 + t;
      const int vcol = idx >> 4, r8 = (idx & 15) * 8;
      bf16x8 v8 = *(const bf16x8*)&L[vcol * 132 + r8];
      const int cc = (n0 + vcol) & 1023;
      const int hh = cc >> 6, d = cc & 63;
      *(bf16x8*)&vto[((size_t)(bq * 16 + hh) * 64 + d) * 2048 + ttb + r8] = v8;
    }
  } else {
    bf16_t* dst = (which == 0) ? qo : ko;
#pragma unroll
    for (int c = 0; c < 8; ++c) {
      const int idx = c * 256 + t;
      const int row = idx >> 4, c8 = (idx & 15) * 8;
      bf16x8 v8 = *(const bf16x8*)&L[row * 132 + c8];
      const int cc = (n0 & 1023) + c8;
      const int hh = cc >> 6, d = cc & 63;
      *(bf16x8*)&dst[((size_t)(bq * 16 + hh) * 2048 + ttb + row) * 64 + d] = v8;
    }
  }
}

// ---------------- flash attention v3: LDS-staged K/V (fragment-order), KVBLK=64 ----------------
__global__ __launch_bounds__(256) void k_attn3(
    const bf16_t* __restrict__ q, const bf16_t* __restrict__ k,
    const bf16_t* __restrict__ vt, const int* __restrict__ dirp,
    bf16_t* __restrict__ a2) {
  const int T = 2048;
  __shared__ __align__(16) bf16_t smem[16384];  // 32 KB: 2 bufs x 16KB
  const int bh = blockIdx.x, b = bh >> 4, h = bh & 15;
  const int jb = blockIdx.y;  // pair {jb, 31-jb}: uniform 33 k64-blocks/block
  const int t = threadIdx.x, lane = t & 63, w = t >> 6;
  const int ln15 = lane & 15, lhi = lane >> 4;
  const bool anti = (*dirp == 1);

  const bf16_t* kbase = k + (size_t)bh * T * 64;
  const bf16_t* vbase = vt + (size_t)bh * 64 * T;

  auto stage = [&](int kc0, int buf) {
    char* Kd = (char*)smem + buf * 16384;
    char* Vd = Kd + 8192;
#pragma unroll
    for (int s = 0; s < 2; ++s) {
      const int qk = s * 4 + (t >> 6);
      const int krow = kc0 + (qk >> 2) * 32 + ((qk >> 1) & 1) * 4 +
                       ((lane & 15) >> 2) * 8 + (lane & 3);
      const int kcolb = (lane >> 4) * 16 + (qk & 1) * 64;
      gld_lds16((const char*)kbase + (size_t)krow * 128 + kcolb,
                Kd + s * 4096 + t * 16);
      const int gv = qk;
      const int vd = (gv & 3) * 16 + (lane & 15);
      gld_lds16((const char*)vbase + (size_t)vd * 4096 + (size_t)kc0 * 2 +
                    (gv >> 2) * 64 + (lane >> 4) * 16,
                Vd + s * 4096 + t * 16);
    }
  };

#pragma unroll 1
  for (int sel = 0; sel < 2; ++sel) {
    const int qt = sel ? (31 - jb) : jb;
    const int q0 = qt * 64 + w * 16;
    const int qrow = q0 + ln15;

    const bf16_t* qp = q + ((size_t)bh * T + qrow) * 64 + lhi * 8;
    bf16x8 qf0 = *(const bf16x8*)qp;
    bf16x8 qf1 = *(const bf16x8*)(qp + 32);

    f32x4 acc[4];
#pragma unroll
    for (int g = 0; g < 4; ++g) acc[g] = (f32x4){0.f, 0.f, 0.f, 0.f};
    float mrun = -3.0e38f, lrun = 0.f;

    const int kt0 = anti ? qt : 0;
    const int nb = anti ? (32 - qt) : (qt + 1);

    stage(kt0 * 64, 0);
#pragma unroll 1
    for (int i = 0; i < nb; ++i) {
      const int kt = kt0 + i;
      const int buf = i & 1;
      if (i + 1 < nb) {
        stage((kt + 1) * 64, buf ^ 1);
        asm volatile("s_waitcnt vmcnt(4)" ::: "memory");
      } else {
        asm volatile("s_waitcnt vmcnt(0)" ::: "memory");
      }
      block_sync();
      const bf16_t* Kb = smem + buf * 8192;  // bf16 units
      const bf16_t* Vb = Kb + 4096;

      float sc[16];
#pragma unroll
      for (int kh = 0; kh < 2; ++kh) {
        bf16x8 k0 = *(const bf16x8*)(Kb + (kh * 4 + 0) * 512 + lane * 8);
        bf16x8 k1 = *(const bf16x8*)(Kb + (kh * 4 + 1) * 512 + lane * 8);
        bf16x8 k2 = *(const bf16x8*)(Kb + (kh * 4 + 2) * 512 + lane * 8);
        bf16x8 k3 = *(const bf16x8*)(Kb + (kh * 4 + 3) * 512 + lane * 8);
        const f32x4 zz = (f32x4){0.f, 0.f, 0.f, 0.f};
        f32x4 slo = __builtin_amdgcn_mfma_f32_16x16x32_bf16(k0, qf0, zz, 0, 0, 0);
        slo = __builtin_amdgcn_mfma_f32_16x16x32_bf16(k1, qf1, slo, 0, 0, 0);
        f32x4 shi = __builtin_amdgcn_mfma_f32_16x16x32_bf16(k2, qf0, zz, 0, 0, 0);
        shi = __builtin_amdgcn_mfma_f32_16x16x32_bf16(k3, qf1, shi, 0, 0, 0);
#pragma unroll
        for (int j = 0; j < 4; ++j) {
          sc[kh * 8 + j] = slo[j];
          sc[kh * 8 + 4 + j] = shi[j];
        }
      }
      if (kt == qt) {  // diagonal block: apply mask
#pragma unroll
        for (int e = 0; e < 16; ++e) {
          const int col = kt * 64 + (e >> 3) * 32 + lhi * 8 + (e & 7);
          const bool ok = anti ? (col >= qrow) : (col <= qrow);
          sc[e] = ok ? sc[e] : -3.0e38f;
        }
      }
      float lmax = sc[0];
#pragma unroll
      for (int e = 1; e < 16; ++e) lmax = fmaxf(lmax, sc[e]);
      if (!__all(lmax <= mrun + 8.f)) {
        float vm = lmax;
        vm = fmaxf(vm, __shfl_xor(vm, 16));
        vm = fmaxf(vm, __shfl_xor(vm, 32));
        const float mn = fmaxf(mrun, vm);
        const float al = __builtin_amdgcn_exp2f(mrun - mn);
        lrun *= al;
#pragma unroll
        for (int g = 0; g < 4; ++g) acc[g] *= al;
        mrun = mn;
      }
      bf16x8 pb0, pb1;
      float rs = 0.f;
#pragma unroll
      for (int e = 0; e < 8; ++e) {
        float p = __builtin_amdgcn_exp2f(sc[e] - mrun);
        rs += p; pb0[e] = (bf16_t)p;
      }
#pragma unroll
      for (int e = 0; e < 8; ++e) {
        float p = __builtin_amdgcn_exp2f(sc[8 + e] - mrun);
        rs += p; pb1[e] = (bf16_t)p;
      }
      lrun += rs;
#pragma unroll
      for (int dg = 0; dg < 4; ++dg) {
        bf16x8 v0 = *(const bf16x8*)(Vb + dg * 512 + lane * 8);
        acc[dg] = __builtin_amdgcn_mfma_f32_16x16x32_bf16(v0, pb0, acc[dg], 0, 0, 0);
      }
#pragma unroll
      for (int dg = 0; dg < 4; ++dg) {
        bf16x8 v1 = *(const bf16x8*)(Vb + (4 + dg) * 512 + lane * 8);
        acc[dg] = __builtin_amdgcn_mfma_f32_16x16x32_bf16(v1, pb1, acc[dg], 0, 0, 0);
      }
      block_sync();
    }

    lrun += __shfl_xor(lrun, 16);
    lrun += __shfl_xor(lrun, 32);
    const float inv = __builtin_amdgcn_rcpf(lrun);
    bf16_t* op = a2 + ((size_t)b * T + qrow) * 1024 + h * 64 + lhi * 4;
#pragma unroll
    for (int g = 0; g < 4; ++g) {
      bf16x4 o4;
#pragma unroll
      for (int jx = 0; jx < 4; ++jx) o4[jx] = (bf16_t)(acc[g][jx] * inv);
      *(bf16x4*)(op + g * 16) = o4;
    }
  }
}

// ---------------- GEMM2 v2: fragment-order LDS, 2-phase pipeline, fp32 out ----------------
__global__ __launch_bounds__(256) void k_gemm_proj(
    const bf16_t* __restrict__ A, const bf16_t* __restrict__ Bt,
    const float* __restrict__ bias, float* __restrict__ out) {
  const int K = 1024;
  __shared__ __align__(16) char smem[32768];
  const int m0 = blockIdx.x * 128, n0 = blockIdx.y * 128;
  const int t = threadIdx.x, lane = t & 63, w = t >> 6;
  const int wr = w >> 1, wc = w & 1;
  const int ln15 = lane & 15, lhi = lane >> 4;

  f32x4 acc[4][4];
#pragma unroll
  for (int m = 0; m < 4; ++m)
#pragma unroll
    for (int n = 0; n < 4; ++n) acc[m][n] = (f32x4){0.f, 0.f, 0.f, 0.f};

  const bf16_t* aSrc = A + (size_t)(m0 + w * 16 + ln15) * K + lhi * 8;
  const bf16_t* bSrc = Bt + (size_t)(n0 + w * 16 + ln15) * K + lhi * 8;
  char* dstA = smem + t * 16;

  auto stageG = [&](int k0, int buf) {
    char* base = dstA + buf * 16384;
    gld_lds16(aSrc + k0, base);
    gld_lds16(aSrc + 64 * K + k0, base + 4096);
    gld_lds16(bSrc + k0, base + 8192);
    gld_lds16(bSrc + 64 * K + k0, base + 12288);
  };

  stageG(0, 0);
  asm volatile("s_waitcnt vmcnt(0)" ::: "memory");
  block_sync();
  int buf = 0;
#pragma unroll 2
  for (int it = 0; it < 32; ++it) {
    if (it + 1 < 32) stageG((it + 1) * 32, buf ^ 1);
    const bf16_t* Asb = (const bf16_t*)(smem + buf * 16384);
    const bf16_t* Bsb = (const bf16_t*)(smem + buf * 16384 + 8192);
    bf16x8 af[4], bfr[4];
#pragma unroll
    for (int m = 0; m < 4; ++m)
      af[m] = *(const bf16x8*)(Asb + (wr * 4 + m) * 512 + lane * 8);
#pragma unroll
    for (int n = 0; n < 4; ++n)
      bfr[n] = *(const bf16x8*)(Bsb + (wc * 4 + n) * 512 + lane * 8);
#pragma unroll
    for (int m = 0; m < 4; ++m)
#pragma unroll
      for (int n = 0; n < 4; ++n)
        acc[m][n] = __builtin_amdgcn_mfma_f32_16x16x32_bf16(af[m], bfr[n], acc[m][n], 0, 0, 0);
    asm volatile("s_waitcnt vmcnt(0)" ::: "memory");
    block_sync();
    buf ^= 1;
  }
#pragma unroll
  for (int n = 0; n < 4; ++n) {
    const int col = n0 + wc * 64 + n * 16 + ln15;
    const float bv = bias[col];
#pragma unroll
    for (int m = 0; m < 4; ++m)
#pragma unroll
      for (int j = 0; j < 4; ++j) {
        const int row = m0 + wr * 64 + m * 16 + lhi * 4 + j;
        out[(size_t)row * 1024 + col] = acc[m][n][j] + bv;
      }
  }
}

extern "C" void kernel_launch(void* const* d_in, const int* in_sizes, int n_in,
                              void* d_out, int out_size, void* d_ws, size_t ws_size,
                              hipStream_t stream) {
  (void)in_sizes; (void)n_in; (void)out_size; (void)ws_size;
  const float* x      = (const float*)d_in[0];
  const int*   dirp   = (const int*)d_in[1];
  const float* qkv_w  = (const float*)d_in[2];
  const float* qkv_b  = (const float*)d_in[3];
  const float* proj_w = (const float*)d_in[4];
  const float* proj_b = (const float*)d_in[5];
  float* out = (float*)d_out;

  char* ws = (char*)d_ws;
  bf16_t* xb   = (bf16_t*)(ws);                       // 16,777,216 B (reused as a2)
  bf16_t* wq_t = (bf16_t*)(ws + 16777216);            //  6,291,456 B
  bf16_t* wp_t = (bf16_t*)(ws + 23068672);            //  2,097,152 B
  bf16_t* qb   = (bf16_t*)(ws + 25165824);            // 16,777,216 B
  bf16_t* kb   = (bf16_t*)(ws + 41943040);            // 16,777,216 B
  bf16_t* vtb  = (bf16_t*)(ws + 58720256);            // 16,777,216 B (end: 75,497,472)
  bf16_t* a2   = xb;

  k_cast<<<8192, 256, 0, stream>>>(x, xb, 2097152);
  k_transpose_cast<<<dim3(96, 32), dim3(32, 8), 0, stream>>>(qkv_w, wq_t, 1024, 3072);
  k_transpose_cast<<<dim3(32, 32), dim3(32, 8), 0, stream>>>(proj_w, wp_t, 1024, 1024);
  k_gemm_qkv<<<dim3(64, 24), 256, 0, stream>>>(xb, wq_t, qkv_b, qb, kb, vtb);
  k_attn3<<<dim3(64, 16), 256, 0, stream>>>(qb, kb, vtb, dirp, a2);
  k_gemm_proj<<<dim3(64, 8), 256, 0, stream>>>(a2, wp_t, proj_b, out);
}

// Round 5
// 204.467 us; speedup vs baseline: 1.0931x; 1.0931x over previous
//
#include <hip/hip_runtime.h>
#include <math.h>

typedef __bf16 bf16_t;
typedef bf16_t bf16x8 __attribute__((ext_vector_type(8)));
typedef bf16_t bf16x4 __attribute__((ext_vector_type(4)));
typedef float  f32x4  __attribute__((ext_vector_type(4)));
typedef float  floatv4 __attribute__((ext_vector_type(4)));

#define AS1 __attribute__((address_space(1)))
#define AS3 __attribute__((address_space(3)))

static __device__ __forceinline__ void gld_lds16(const void* g, void* l) {
  __builtin_amdgcn_global_load_lds((const AS1 unsigned int*)g,
                                   (AS3 unsigned int*)l, 16, 0, 0);
}
static __device__ __forceinline__ void block_sync() {
  asm volatile("" ::: "memory");
  __builtin_amdgcn_s_barrier();
  asm volatile("" ::: "memory");
}

// ---------------- cast f32 -> bf16, 4 elems/thread ----------------
__global__ __launch_bounds__(256) void k_cast(const float* __restrict__ in,
                                              bf16_t* __restrict__ out, int n4) {
  int i = blockIdx.x * 256 + threadIdx.x;
  if (i >= n4) return;
  floatv4 v = ((const floatv4*)in)[i];
  bf16x4 o;
  o.x = (bf16_t)v.x; o.y = (bf16_t)v.y; o.z = (bf16_t)v.z; o.w = (bf16_t)v.w;
  ((bf16x4*)out)[i] = o;
}

// ---------------- transpose + cast: in f32 [R][Cc] -> out bf16 [Cc][R] ----------------
__global__ __launch_bounds__(256) void k_transpose_cast(const float* __restrict__ in,
                                                        bf16_t* __restrict__ out,
                                                        int R, int Cc) {
  __shared__ float tile[32][33];
  int c0 = blockIdx.x * 32, r0 = blockIdx.y * 32;
  int tx = threadIdx.x, ty = threadIdx.y;  // 32 x 8
#pragma unroll
  for (int i = 0; i < 32; i += 8)
    tile[ty + i][tx] = in[(size_t)(r0 + ty + i) * Cc + c0 + tx];
  __syncthreads();
#pragma unroll
  for (int i = 0; i < 32; i += 8)
    out[(size_t)(c0 + ty + i) * R + r0 + tx] = (bf16_t)tile[tx][ty + i];
}

// ============ GEMM template v3: 256x128 tile, BK=64, 8 waves, 3-buffer depth-2 ============
// Fragment-order LDS per buffer (48KB): A = 16 frags x 2 kk x 64 lanes x 16B (32KB),
// B (at +32768) = 8 frags x 2 kk x 64 lanes x 16B (16KB).
// Thread t stages: A chunks c=0..3 at byte c*8192 + t*16; B chunks c=0..1 at 32768 + c*8192 + t*16.
// Source: row = base + (t>>7)*16 + (t&15) + c*64, col = k0 + ((t>>6)&1)*32 + ((t&63)>>4)*8.
// Read: frag f, slice kk: byte (f*2+kk)*1024 + lane*16 (lane-linear, conflict-free).

// ---------------- GEMM1: qkv = X @ Wt^T, scatter to q(scaled)/k/v(trans) bf16 ----------------
__global__ __launch_bounds__(512, 2) void k_gemm_qkv(
    const bf16_t* __restrict__ A, const bf16_t* __restrict__ Bt,
    const float* __restrict__ bias,
    bf16_t* __restrict__ qo, bf16_t* __restrict__ ko, bf16_t* __restrict__ vto) {
  const int K = 1024;
  __shared__ __align__(16) char smem[147456];  // 3 x 48KB; epilogue reuses
  const int m0 = blockIdx.x * 256, n0 = blockIdx.y * 128;
  const int t = threadIdx.x, lane = t & 63, wv = t >> 6;
  const int ln15 = lane & 15, lhi = lane >> 4;
  const int wr = wv >> 1, wc = wv & 1;

  f32x4 acc[4][4];
#pragma unroll
  for (int m = 0; m < 4; ++m)
#pragma unroll
    for (int n = 0; n < 4; ++n) acc[m][n] = (f32x4){0.f, 0.f, 0.f, 0.f};

  const bf16_t* aSrc = A + (size_t)(m0 + (t >> 7) * 16 + ln15) * K + ((t >> 6) & 1) * 32 + lhi * 8;
  const bf16_t* bSrc = Bt + (size_t)(n0 + (t >> 7) * 16 + ln15) * K + ((t >> 6) & 1) * 32 + lhi * 8;
  const int dstOff = t * 16;

  auto stage = [&](int k0, char* base) {
#pragma unroll
    for (int c = 0; c < 4; ++c)
      gld_lds16(aSrc + (size_t)c * 64 * K + k0, base + c * 8192 + dstOff);
#pragma unroll
    for (int c = 0; c < 2; ++c)
      gld_lds16(bSrc + (size_t)c * 64 * K + k0, base + 32768 + c * 8192 + dstOff);
  };
  auto compute = [&](const char* base) {
    const bf16_t* Ab = (const bf16_t*)base;
    const bf16_t* Bb = (const bf16_t*)(base + 32768);
#pragma unroll
    for (int kk = 0; kk < 2; ++kk) {
      bf16x8 af[4], bf[4];
#pragma unroll
      for (int m = 0; m < 4; ++m)
        af[m] = *(const bf16x8*)(Ab + ((wr * 4 + m) * 2 + kk) * 512 + lane * 8);
#pragma unroll
      for (int n = 0; n < 4; ++n)
        bf[n] = *(const bf16x8*)(Bb + ((wc * 4 + n) * 2 + kk) * 512 + lane * 8);
      __builtin_amdgcn_s_setprio(1);
#pragma unroll
      for (int m = 0; m < 4; ++m)
#pragma unroll
        for (int n = 0; n < 4; ++n)
          acc[m][n] = __builtin_amdgcn_mfma_f32_16x16x32_bf16(af[m], bf[n], acc[m][n], 0, 0, 0);
      __builtin_amdgcn_s_setprio(0);
    }
  };

  char* pc = smem;
  char* p1 = smem + 49152;
  char* p2 = smem + 98304;
  stage(0, pc);
  stage(64, p1);
#pragma unroll 1
  for (int it = 0; it < 16; ++it) {
    if (it + 2 < 16) {
      stage((it + 2) * 64, p2);
      asm volatile("s_waitcnt vmcnt(12)" ::: "memory");
    } else if (it + 1 < 16) {
      asm volatile("s_waitcnt vmcnt(6)" ::: "memory");
    } else {
      asm volatile("s_waitcnt vmcnt(0)" ::: "memory");
    }
    block_sync();
    compute(pc);
    block_sync();
    char* old = pc; pc = p1; p1 = p2; p2 = old;
  }

  // epilogue through LDS for coalesced 16B stores
  const int which = n0 >> 10;  // uniform per block: 0=q 1=k 2=v
  const float bscale = (which == 0) ? 0.18033688011112042f : 1.0f;  // 0.125*log2(e)
  bf16_t* L = (bf16_t*)smem;
#pragma unroll
  for (int n = 0; n < 4; ++n) {
    const int col = wc * 64 + n * 16 + ln15;
    const float bv = bias[n0 + col];
#pragma unroll
    for (int m = 0; m < 4; ++m)
#pragma unroll
      for (int j = 0; j < 4; ++j) {
        const int row = wr * 64 + m * 16 + lhi * 4 + j;
        const bf16_t ob = (bf16_t)((acc[m][n][j] + bv) * bscale);
        if (which == 2) L[col * 264 + row] = ob;   // [128][264] col-major
        else            L[row * 132 + col] = ob;   // [256][132] row-major
      }
  }
  block_sync();
  const int bq = m0 >> 11, ttb = m0 & 2047;
  if (which == 2) {
#pragma unroll
    for (int c = 0; c < 8; ++c) {
      const int idx = c * 512 + t;
      const int vcol = idx >> 5, r8 = (idx & 31) * 8;
      bf16x8 v8 = *(const bf16x8*)&L[vcol * 264 + r8];
      const int cc = (n0 + vcol) & 1023;
      const int hh = cc >> 6, d = cc & 63;
      *(bf16x8*)&vto[((size_t)(bq * 16 + hh) * 64 + d) * 2048 + ttb + r8] = v8;
    }
  } else {
    bf16_t* dst = (which == 0) ? qo : ko;
#pragma unroll
    for (int c = 0; c < 8; ++c) {
      const int idx = c * 512 + t;
      const int row = idx >> 4, c8 = (idx & 15) * 8;
      bf16x8 v8 = *(const bf16x8*)&L[row * 132 + c8];
      const int cc = (n0 & 1023) + c8;
      const int hh = cc >> 6, d = cc & 63;
      *(bf16x8*)&dst[((size_t)(bq * 16 + hh) * 2048 + ttb + row) * 64 + d] = v8;
    }
  }
}

// ---------------- flash attention v3: LDS-staged K/V (fragment-order), KVBLK=64 ----------------
__global__ __launch_bounds__(256) void k_attn3(
    const bf16_t* __restrict__ q, const bf16_t* __restrict__ k,
    const bf16_t* __restrict__ vt, const int* __restrict__ dirp,
    bf16_t* __restrict__ a2) {
  const int T = 2048;
  __shared__ __align__(16) bf16_t smem[16384];  // 32 KB: 2 bufs x 16KB
  const int bh = blockIdx.x, b = bh >> 4, h = bh & 15;
  const int jb = blockIdx.y;  // pair {jb, 31-jb}: uniform 33 k64-blocks/block
  const int t = threadIdx.x, lane = t & 63, w = t >> 6;
  const int ln15 = lane & 15, lhi = lane >> 4;
  const bool anti = (*dirp == 1);

  const bf16_t* kbase = k + (size_t)bh * T * 64;
  const bf16_t* vbase = vt + (size_t)bh * 64 * T;

  auto stage = [&](int kc0, int buf) {
    char* Kd = (char*)smem + buf * 16384;
    char* Vd = Kd + 8192;
#pragma unroll
    for (int s = 0; s < 2; ++s) {
      const int qk = s * 4 + (t >> 6);
      const int krow = kc0 + (qk >> 2) * 32 + ((qk >> 1) & 1) * 4 +
                       ((lane & 15) >> 2) * 8 + (lane & 3);
      const int kcolb = (lane >> 4) * 16 + (qk & 1) * 64;
      gld_lds16((const char*)kbase + (size_t)krow * 128 + kcolb,
                Kd + s * 4096 + t * 16);
      const int gv = qk;
      const int vd = (gv & 3) * 16 + (lane & 15);
      gld_lds16((const char*)vbase + (size_t)vd * 4096 + (size_t)kc0 * 2 +
                    (gv >> 2) * 64 + (lane >> 4) * 16,
                Vd + s * 4096 + t * 16);
    }
  };

#pragma unroll 1
  for (int sel = 0; sel < 2; ++sel) {
    const int qt = sel ? (31 - jb) : jb;
    const int q0 = qt * 64 + w * 16;
    const int qrow = q0 + ln15;

    const bf16_t* qp = q + ((size_t)bh * T + qrow) * 64 + lhi * 8;
    bf16x8 qf0 = *(const bf16x8*)qp;
    bf16x8 qf1 = *(const bf16x8*)(qp + 32);

    f32x4 acc[4];
#pragma unroll
    for (int g = 0; g < 4; ++g) acc[g] = (f32x4){0.f, 0.f, 0.f, 0.f};
    float mrun = -3.0e38f, lrun = 0.f;

    const int kt0 = anti ? qt : 0;
    const int nb = anti ? (32 - qt) : (qt + 1);

    stage(kt0 * 64, 0);
#pragma unroll 1
    for (int i = 0; i < nb; ++i) {
      const int kt = kt0 + i;
      const int buf = i & 1;
      if (i + 1 < nb) {
        stage((kt + 1) * 64, buf ^ 1);
        asm volatile("s_waitcnt vmcnt(4)" ::: "memory");
      } else {
        asm volatile("s_waitcnt vmcnt(0)" ::: "memory");
      }
      block_sync();
      const bf16_t* Kb = smem + buf * 8192;  // bf16 units
      const bf16_t* Vb = Kb + 4096;

      float sc[16];
#pragma unroll
      for (int kh = 0; kh < 2; ++kh) {
        bf16x8 k0 = *(const bf16x8*)(Kb + (kh * 4 + 0) * 512 + lane * 8);
        bf16x8 k1 = *(const bf16x8*)(Kb + (kh * 4 + 1) * 512 + lane * 8);
        bf16x8 k2 = *(const bf16x8*)(Kb + (kh * 4 + 2) * 512 + lane * 8);
        bf16x8 k3 = *(const bf16x8*)(Kb + (kh * 4 + 3) * 512 + lane * 8);
        const f32x4 zz = (f32x4){0.f, 0.f, 0.f, 0.f};
        f32x4 slo = __builtin_amdgcn_mfma_f32_16x16x32_bf16(k0, qf0, zz, 0, 0, 0);
        slo = __builtin_amdgcn_mfma_f32_16x16x32_bf16(k1, qf1, slo, 0, 0, 0);
        f32x4 shi = __builtin_amdgcn_mfma_f32_16x16x32_bf16(k2, qf0, zz, 0, 0, 0);
        shi = __builtin_amdgcn_mfma_f32_16x16x32_bf16(k3, qf1, shi, 0, 0, 0);
#pragma unroll
        for (int j = 0; j < 4; ++j) {
          sc[kh * 8 + j] = slo[j];
          sc[kh * 8 + 4 + j] = shi[j];
        }
      }
      if (kt == qt) {  // diagonal block: apply mask
#pragma unroll
        for (int e = 0; e < 16; ++e) {
          const int col = kt * 64 + (e >> 3) * 32 + lhi * 8 + (e & 7);
          const bool ok = anti ? (col >= qrow) : (col <= qrow);
          sc[e] = ok ? sc[e] : -3.0e38f;
        }
      }
      float lmax = sc[0];
#pragma unroll
      for (int e = 1; e < 16; ++e) lmax = fmaxf(lmax, sc[e]);
      if (!__all(lmax <= mrun + 8.f)) {
        float vm = lmax;
        vm = fmaxf(vm, __shfl_xor(vm, 16));
        vm = fmaxf(vm, __shfl_xor(vm, 32));
        const float mn = fmaxf(mrun, vm);
        const float al = __builtin_amdgcn_exp2f(mrun - mn);
        lrun *= al;
#pragma unroll
        for (int g = 0; g < 4; ++g) acc[g] *= al;
        mrun = mn;
      }
      bf16x8 pb0, pb1;
      float rs = 0.f;
#pragma unroll
      for (int e = 0; e < 8; ++e) {
        float p = __builtin_amdgcn_exp2f(sc[e] - mrun);
        rs += p; pb0[e] = (bf16_t)p;
      }
#pragma unroll
      for (int e = 0; e < 8; ++e) {
        float p = __builtin_amdgcn_exp2f(sc[8 + e] - mrun);
        rs += p; pb1[e] = (bf16_t)p;
      }
      lrun += rs;
#pragma unroll
      for (int dg = 0; dg < 4; ++dg) {
        bf16x8 v0 = *(const bf16x8*)(Vb + dg * 512 + lane * 8);
        acc[dg] = __builtin_amdgcn_mfma_f32_16x16x32_bf16(v0, pb0, acc[dg], 0, 0, 0);
      }
#pragma unroll
      for (int dg = 0; dg < 4; ++dg) {
        bf16x8 v1 = *(const bf16x8*)(Vb + (4 + dg) * 512 + lane * 8);
        acc[dg] = __builtin_amdgcn_mfma_f32_16x16x32_bf16(v1, pb1, acc[dg], 0, 0, 0);
      }
      block_sync();
    }

    lrun += __shfl_xor(lrun, 16);
    lrun += __shfl_xor(lrun, 32);
    const float inv = __builtin_amdgcn_rcpf(lrun);
    bf16_t* op = a2 + ((size_t)b * T + qrow) * 1024 + h * 64 + lhi * 4;
#pragma unroll
    for (int g = 0; g < 4; ++g) {
      bf16x4 o4;
#pragma unroll
      for (int jx = 0; jx < 4; ++jx) o4[jx] = (bf16_t)(acc[g][jx] * inv);
      *(bf16x4*)(op + g * 16) = o4;
    }
  }
}

// ---------------- GEMM2: out = A2 @ Wp^T + bias, fp32 out ----------------
__global__ __launch_bounds__(512, 2) void k_gemm_proj(
    const bf16_t* __restrict__ A, const bf16_t* __restrict__ Bt,
    const float* __restrict__ bias, float* __restrict__ out) {
  const int K = 1024;
  __shared__ __align__(16) char smem[147456];
  const int m0 = blockIdx.x * 256, n0 = blockIdx.y * 128;
  const int t = threadIdx.x, lane = t & 63, wv = t >> 6;
  const int ln15 = lane & 15, lhi = lane >> 4;
  const int wr = wv >> 1, wc = wv & 1;

  f32x4 acc[4][4];
#pragma unroll
  for (int m = 0; m < 4; ++m)
#pragma unroll
    for (int n = 0; n < 4; ++n) acc[m][n] = (f32x4){0.f, 0.f, 0.f, 0.f};

  const bf16_t* aSrc = A + (size_t)(m0 + (t >> 7) * 16 + ln15) * K + ((t >> 6) & 1) * 32 + lhi * 8;
  const bf16_t* bSrc = Bt + (size_t)(n0 + (t >> 7) * 16 + ln15) * K + ((t >> 6) & 1) * 32 + lhi * 8;
  const int dstOff = t * 16;

  auto stage = [&](int k0, char* base) {
#pragma unroll
    for (int c = 0; c < 4; ++c)
      gld_lds16(aSrc + (size_t)c * 64 * K + k0, base + c * 8192 + dstOff);
#pragma unroll
    for (int c = 0; c < 2; ++c)
      gld_lds16(bSrc + (size_t)c * 64 * K + k0, base + 32768 + c * 8192 + dstOff);
  };
  auto compute = [&](const char* base) {
    const bf16_t* Ab = (const bf16_t*)base;
    const bf16_t* Bb = (const bf16_t*)(base + 32768);
#pragma unroll
    for (int kk = 0; kk < 2; ++kk) {
      bf16x8 af[4], bf[4];
#pragma unroll
      for (int m = 0; m < 4; ++m)
        af[m] = *(const bf16x8*)(Ab + ((wr * 4 + m) * 2 + kk) * 512 + lane * 8);
#pragma unroll
      for (int n = 0; n < 4; ++n)
        bf[n] = *(const bf16x8*)(Bb + ((wc * 4 + n) * 2 + kk) * 512 + lane * 8);
      __builtin_amdgcn_s_setprio(1);
#pragma unroll
      for (int m = 0; m < 4; ++m)
#pragma unroll
        for (int n = 0; n < 4; ++n)
          acc[m][n] = __builtin_amdgcn_mfma_f32_16x16x32_bf16(af[m], bf[n], acc[m][n], 0, 0, 0);
      __builtin_amdgcn_s_setprio(0);
    }
  };

  char* pc = smem;
  char* p1 = smem + 49152;
  char* p2 = smem + 98304;
  stage(0, pc);
  stage(64, p1);
#pragma unroll 1
  for (int it = 0; it < 16; ++it) {
    if (it + 2 < 16) {
      stage((it + 2) * 64, p2);
      asm volatile("s_waitcnt vmcnt(12)" ::: "memory");
    } else if (it + 1 < 16) {
      asm volatile("s_waitcnt vmcnt(6)" ::: "memory");
    } else {
      asm volatile("s_waitcnt vmcnt(0)" ::: "memory");
    }
    block_sync();
    compute(pc);
    block_sync();
    char* old = pc; pc = p1; p1 = p2; p2 = old;
  }

#pragma unroll
  for (int n = 0; n < 4; ++n) {
    const int col = n0 + wc * 64 + n * 16 + ln15;
    const float bv = bias[col];
#pragma unroll
    for (int m = 0; m < 4; ++m)
#pragma unroll
      for (int j = 0; j < 4; ++j) {
        const int row = m0 + wr * 64 + m * 16 + lhi * 4 + j;
        out[(size_t)row * 1024 + col] = acc[m][n][j] + bv;
      }
  }
}

extern "C" void kernel_launch(void* const* d_in, const int* in_sizes, int n_in,
                              void* d_out, int out_size, void* d_ws, size_t ws_size,
                              hipStream_t stream) {
  (void)in_sizes; (void)n_in; (void)out_size; (void)ws_size;
  const float* x      = (const float*)d_in[0];
  const int*   dirp   = (const int*)d_in[1];
  const float* qkv_w  = (const float*)d_in[2];
  const float* qkv_b  = (const float*)d_in[3];
  const float* proj_w = (const float*)d_in[4];
  const float* proj_b = (const float*)d_in[5];
  float* out = (float*)d_out;

  char* ws = (char*)d_ws;
  bf16_t* xb   = (bf16_t*)(ws);                       // 16,777,216 B (reused as a2)
  bf16_t* wq_t = (bf16_t*)(ws + 16777216);            //  6,291,456 B
  bf16_t* wp_t = (bf16_t*)(ws + 23068672);            //  2,097,152 B
  bf16_t* qb   = (bf16_t*)(ws + 25165824);            // 16,777,216 B
  bf16_t* kb   = (bf16_t*)(ws + 41943040);            // 16,777,216 B
  bf16_t* vtb  = (bf16_t*)(ws + 58720256);            // 16,777,216 B (end: 75,497,472)
  bf16_t* a2   = xb;

  k_cast<<<8192, 256, 0, stream>>>(x, xb, 2097152);
  k_transpose_cast<<<dim3(96, 32), dim3(32, 8), 0, stream>>>(qkv_w, wq_t, 1024, 3072);
  k_transpose_cast<<<dim3(32, 32), dim3(32, 8), 0, stream>>>(proj_w, wp_t, 1024, 1024);
  k_gemm_qkv<<<dim3(32, 24), 512, 0, stream>>>(xb, wq_t, qkv_b, qb, kb, vtb);
  k_attn3<<<dim3(64, 16), 256, 0, stream>>>(qb, kb, vtb, dirp, a2);
  k_gemm_proj<<<dim3(32, 8), 512, 0, stream>>>(a2, wp_t, proj_b, out);
}